// Round 2
// baseline (160.150 us; speedup 1.0000x reference)
//
#include <hip/hip_runtime.h>
#include <hip/hip_bf16.h>

#define BATCH 2
#define SLEN 2048
#define NH 12
#define DM 768
#define DH 64
#define ROWS (BATCH*SLEN)   // 4096
#define NQKV (3*DM)         // 2304
#define NCHUNK 40           // split-K chunks per bh (q-tile=128, chunk = up to 8 k-tiles)

typedef __attribute__((ext_vector_type(8))) short bf16x8;
typedef __attribute__((ext_vector_type(4))) float f32x4;
typedef __attribute__((ext_vector_type(16))) float f32x16;
typedef unsigned short u16;
typedef unsigned int u32;
typedef __attribute__((ext_vector_type(4))) unsigned short u16x4;
typedef __attribute__((ext_vector_type(8))) unsigned short u16x8;

__device__ __forceinline__ u16 f2b(float f) {
    unsigned int u = __builtin_bit_cast(unsigned int, f);
    unsigned int r = (u + 0x7FFFu + ((u >> 16) & 1u)) >> 16;
    return (u16)r;
}
__device__ __forceinline__ float b2f(u16 v) {
    unsigned int u = ((unsigned int)v) << 16;
    return __builtin_bit_cast(float, u);
}

// async global->LDS, 16B per lane. LDS dest = wave-uniform base + lane*16.
__device__ __forceinline__ void gload16(const u16* g, u16* l) {
    __builtin_amdgcn_global_load_lds(
        (const __attribute__((address_space(1))) unsigned int*)g,
        (__attribute__((address_space(3))) unsigned int*)l,
        16, 0, 0);
}

// ---------------- merged pack kernel (x -> bf16, W_QKV -> Bt layout, W_O -> Bt layout) ----
// grid 2112 = 1536 (x) + 432 (wqkv) + 144 (wo); branch is block-uniform.

__global__ __launch_bounds__(256) void pack_all(const float* __restrict__ x,
                                                const float* __restrict__ WQ, const float* __restrict__ WK,
                                                const float* __restrict__ WV, const float* __restrict__ WO,
                                                u16* __restrict__ xb, u16* __restrict__ wqkv,
                                                u16* __restrict__ wo) {
    __shared__ u16 L[64 * 72];
    int blk = blockIdx.x;
    int t = threadIdx.x;
    if (blk < 1536) {
        int i = blk * 256 + t;
        const float4* xv = (const float4*)x;
        float4 a = xv[i * 2], b = xv[i * 2 + 1];
        u16x8 o;
        o[0] = f2b(a.x); o[1] = f2b(a.y); o[2] = f2b(a.z); o[3] = f2b(a.w);
        o[4] = f2b(b.x); o[5] = f2b(b.y); o[6] = f2b(b.z); o[7] = f2b(b.w);
        *(u16x8*)(xb + (size_t)i * 8) = o;
    } else if (blk < 1968) {
        int idx = blk - 1536;
        int mt = idx % 12, h = (idx / 12) % 12, sel = idx / 144;
        const float* W = sel == 0 ? WQ : (sel == 1 ? WK : WV);
        const float* src = W + ((size_t)h * DM + mt * 64) * DH;
        for (int j = 0; j < 4; j++) {
            int i = t + 256 * j;
            int r = i >> 4, cf = i & 15;
            float4 v = ((const float4*)src)[i];
            u16x4 o; o[0] = f2b(v.x); o[1] = f2b(v.y); o[2] = f2b(v.z); o[3] = f2b(v.w);
            *(u16x4*)&L[r * 72 + cf * 4] = o;
        }
        __syncthreads();
        u16* orow = wqkv + ((size_t)(sel * DM + h * DH)) * DM + mt * 64;
        for (int j = 0; j < 16; j++) {
            int e = t + 256 * j;
            int d = e >> 6, mm = e & 63;
            orow[(size_t)d * DM + mm] = L[mm * 72 + d];
        }
    } else {
        int idx = blk - 1968;
        int bi = idx % 12, bj = idx / 12;
        for (int j = 0; j < 4; j++) {
            int i = t + 256 * j;
            int r = i >> 4, cf = i & 15;
            float4 v = ((const float4*)(WO + (size_t)(bi * 64 + r) * DM + bj * 64))[cf];
            u16x4 o; o[0] = f2b(v.x); o[1] = f2b(v.y); o[2] = f2b(v.z); o[3] = f2b(v.w);
            *(u16x4*)&L[r * 72 + cf * 4] = o;
        }
        __syncthreads();
        for (int j = 0; j < 16; j++) {
            int e = t + 256 * j;
            int c = e >> 6, r = e & 63;
            wo[(size_t)(bj * 64 + c) * DM + bi * 64 + r] = L[r * 72 + c];
        }
    }
}

// ---------------- QKV GEMM (128x96 tile, gload16 staging, XOR-swizzled LDS) ----
// grid 24x32 = 768 blocks -> one full residency wave at 3 blocks/CU, no remainder.

__global__ __launch_bounds__(256) void gemm_qkv(const u16* __restrict__ A, const u16* __restrict__ Bt,
                                                const float* __restrict__ bQ, const float* __restrict__ bK,
                                                const float* __restrict__ bV,
                                                u16* __restrict__ Qb, u16* __restrict__ Kb, u16* __restrict__ Vb) {
    __shared__ u16 Al[128 * 64];
    __shared__ u16 Bl[96 * 64];
    int t = threadIdx.x;
    int n0 = blockIdx.x * 96, m0 = blockIdx.y * 128;
    int lane = t & 63, w = t >> 6;
    int ln = lane & 15, qd = lane >> 4;
    int wr = (w & 1) * 64, wc = (w >> 1) * 48;
    int srow = lane >> 3, slot = lane & 7;
    f32x4 acc[4][3] = {};

    for (int kt = 0; kt < DM / 64; kt++) {
        __syncthreads();
        for (int j = 0; j < 4; j++) {
            int r = w * 32 + j * 8 + srow;
            int gc = slot ^ (r & 7);
            gload16(A + (size_t)(m0 + r) * DM + kt * 64 + gc * 8, &Al[(w * 32 + j * 8) * 64]);
        }
        for (int j = 0; j < 3; j++) {
            int r = w * 24 + j * 8 + srow;
            int gc = slot ^ (r & 7);
            gload16(Bt + (size_t)(n0 + r) * DM + kt * 64 + gc * 8, &Bl[(w * 24 + j * 8) * 64]);
        }
        __syncthreads();   // drains vmcnt -> tile visible
        for (int ks = 0; ks < 2; ks++) {
            int sl = ((ks * 4 + qd) ^ (ln & 7)) * 8;
            bf16x8 af[4], bfr[3];
            for (int rt = 0; rt < 4; rt++)
                af[rt] = *(const bf16x8*)&Al[(wr + rt * 16 + ln) * 64 + sl];
            for (int ct = 0; ct < 3; ct++)
                bfr[ct] = *(const bf16x8*)&Bl[(wc + ct * 16 + ln) * 64 + sl];
            for (int rt = 0; rt < 4; rt++)
                for (int ct = 0; ct < 3; ct++)
                    acc[rt][ct] = __builtin_amdgcn_mfma_f32_16x16x32_bf16(af[rt], bfr[ct], acc[rt][ct], 0, 0, 0);
        }
    }
    int sel = n0 / DM;                   // 768/96 = 8 tiles per sel -> uniform per block
    if (sel == 2) {
        for (int ct = 0; ct < 3; ct++) {
            int col = n0 - 2 * DM + wc + ct * 16 + ln;
            int hh = col >> 6, dd = col & 63;
            float bv = bV[col];
            for (int rt = 0; rt < 4; rt++) {
                int row = m0 + wr + rt * 16 + qd * 4;
                int bb = row >> 11, ss = row & 2047;
                u16x4 pk;
                for (int r = 0; r < 4; r++) pk[r] = f2b(acc[rt][ct][r] + bv);
                *(u16x4*)&Vb[(((size_t)bb * NH + hh) * DH + dd) * SLEN + ss] = pk;
            }
        }
    } else {
        const float* bias = sel == 0 ? bQ : bK;
        u16* Out = sel == 0 ? Qb : Kb;
        const float qs = sel == 0 ? 0.125f * 1.44269504f : 1.0f;
        for (int ct = 0; ct < 3; ct++) {
            int col = n0 - sel * DM + wc + ct * 16 + ln;
            int hh = col >> 6, dd = col & 63;
            float bv = bias[col];
            for (int rt = 0; rt < 4; rt++) {
                int row = m0 + wr + rt * 16 + qd * 4;
                for (int r = 0; r < 4; r++) {
                    int rg = row + r;
                    int bb = rg >> 11, ss = rg & 2047;
                    Out[(((size_t)bb * NH + hh) * SLEN + ss) * DH + dd] = f2b((acc[rt][ct][r] + bv) * qs);
                }
            }
        }
    }
}

// ---------------- split-K flash attention, 32x32 MFMA, LDS-routed P ----
// q-tile = 128 rows, 4 waves x 32q. Per 64-k tile per wave: 8 QK MFMA + 8 PV MFMA
// + 4 ones-MFMA (l). K/V staged via gload16 into XOR-swizzled linear LDS.
// P goes through a wave-private LDS buffer: store uint2 bf16-pairs at the D-layout
// rows (crow = (r&3)+8*(r>>2)+4h), read back bf16x8 at cc*16+8h -- the exact
// k-redistribution needed for the PV B-operand, done by addressing only.
// grid 960 = 40 chunks x 24 bh at ~4 blocks/CU; cid = 39 - blk/24 (LPT);
// bh = (blk%24&7)*3 + (blk%24>>3) keeps 3 bh per XCD (K/V L2 residency).

__device__ __forceinline__ void cid2qc(int cid, int& qt, int& c, int& nc) {
    if (cid < 4)       { qt = cid;                   c = 0;               nc = 1; }
    else if (cid < 12) { qt = 4 + ((cid - 4) >> 1);  c = (cid - 4) & 1;   nc = 2; }
    else if (cid < 24) { qt = 8 + (cid - 12) / 3;    c = (cid - 12) % 3;  nc = 3; }
    else               { qt = 12 + ((cid - 24) >> 2); c = (cid - 24) & 3; nc = 4; }
}

__global__ __launch_bounds__(256, 4) void attn(const u16* __restrict__ Qb, const u16* __restrict__ Kb,
                                               const u16* __restrict__ Vtg,
                                               u16* __restrict__ Po, float* __restrict__ Plv) {
    __shared__ u16 Kl[64 * 64];
    __shared__ u16 Vt[64 * 64];          // [d][k]
    __shared__ u16 Pq[4][32 * 72];       // wave-private P: [q-local 32][k 64 (+pad)]
    int blk = blockIdx.x;
    int cid = (NCHUNK - 1) - blk / 24;
    int j24 = blk % 24;
    int bh = (j24 & 7) * 3 + (j24 >> 3);
    int qt, c, nc;
    cid2qc(cid, qt, c, nc);
    int ntiles = 2 * qt + 2;
    int kt0 = c * ntiles / nc, kt1 = (c + 1) * ntiles / nc;
    const u16* Qp = Qb + (size_t)bh * SLEN * DH;
    const u16* Kp = Kb + (size_t)bh * SLEN * DH;
    const u16* Vp = Vtg + (size_t)bh * SLEN * DH;  // [d][s]
    int t = threadIdx.x, lane = t & 63, w = t >> 6;
    int l31 = lane & 31, h = lane >> 5;
    int qg = qt * 128 + w * 32 + l31;
    int srow = lane >> 3, slot = lane & 7;

    // Q fragments (B-operand): col q = lane&31, contraction d = ks*16 + 8h + e
    bf16x8 qf[4];
    for (int ks = 0; ks < 4; ks++)
        qf[ks] = *(const bf16x8*)(Qp + (size_t)qg * DH + ks * 16 + h * 8);

    bf16x8 onesf;
    for (int e = 0; e < 8; e++) onesf[e] = (short)0x3F80;   // bf16 1.0

    f32x16 o[2] = {};    // o[d][q]: col q=lane&31, d = db*32 + (reg&3)+8*(reg>>2)+4h
    f32x16 oL = {};      // l accumulator (all rows identical)
    u16* Pw = Pq[w];

    for (int kt = kt0; kt < kt1; kt++) {
        int k0 = kt * 64;
        __syncthreads();
        for (int j = 0; j < 2; j++) {
            int r = w * 16 + j * 8 + srow;
            int gc = slot ^ (r & 7);
            gload16(Kp + (size_t)(k0 + r) * DH + gc * 8, &Kl[(w * 16 + j * 8) * 64]);
            gload16(Vp + (size_t)r * SLEN + k0 + gc * 8, &Vt[(w * 16 + j * 8) * 64]);
        }
        __syncthreads();   // drains vmcnt -> tile visible

        for (int kb = 0; kb < 2; kb++) {
            // QK^T: S[32k x 32q] = K_rows x Q
            f32x16 sf = {};
            for (int ks = 0; ks < 4; ks++) {
                int row = kb * 32 + l31;
                bf16x8 kf = *(const bf16x8*)&Kl[row * 64 + (((ks * 2 + h) ^ (row & 7)) * 8)];
                sf = __builtin_amdgcn_mfma_f32_32x32x16_bf16(kf, qf[ks], sf, 0, 0, 0);
            }
            if (k0 + 63 > qt * 128 + w * 32) {          // diagonal region, wave-uniform
                for (int r = 0; r < 16; r++) {
                    int kg = k0 + kb * 32 + (r & 3) + 8 * (r >> 2) + 4 * h;
                    if (kg > qg) sf[r] = -1e30f;
                }
            }
            // exp2 + truncate-to-bf16 pack via v_perm (consecutive-k pairs)
            u32 pr[8];
            for (int p = 0; p < 8; p++) {
                u32 e0 = __builtin_bit_cast(u32, exp2f(sf[2 * p]));
                u32 e1 = __builtin_bit_cast(u32, exp2f(sf[2 * p + 1]));
                pr[p] = __builtin_amdgcn_perm(e1, e0, 0x07060302u);
            }
            // store P[q=l31][k] pairs: regs (2p,2p+1) -> k = crow(2p,h) = {0,8,16,24}+4h
            {
                uint2 s;
                s.x = pr[0]; s.y = pr[1];
                *(uint2*)&Pw[l31 * 72 + kb * 32 + 4 * h] = s;
                s.x = pr[2]; s.y = pr[3];
                *(uint2*)&Pw[l31 * 72 + kb * 32 + 8 + 4 * h] = s;
                s.x = pr[4]; s.y = pr[5];
                *(uint2*)&Pw[l31 * 72 + kb * 32 + 16 + 4 * h] = s;
                s.x = pr[6]; s.y = pr[7];
                *(uint2*)&Pw[l31 * 72 + kb * 32 + 24 + 4 * h] = s;
            }
            // PV: read B-fragments (col q=l31, k = cc*16 + 8h + e) straight from LDS
            for (int cc = 0; cc < 2; cc++) {
                bf16x8 pf = *(const bf16x8*)&Pw[l31 * 72 + kb * 32 + cc * 16 + 8 * h];
                int ch4 = kb * 2 + cc;
                oL = __builtin_amdgcn_mfma_f32_32x32x16_bf16(onesf, pf, oL, 0, 0, 0);
                for (int db = 0; db < 2; db++) {
                    int row = db * 32 + l31;
                    bf16x8 vf = *(const bf16x8*)&Vt[row * 64 + (((ch4 * 2 + h) ^ (row & 7)) * 8)];
                    o[db] = __builtin_amdgcn_mfma_f32_32x32x16_bf16(vf, pf, o[db], 0, 0, 0);
                }
            }
        }
    }

    size_t pid = (size_t)bh * NCHUNK + cid;
    u16* op = Po + pid * (128 * 64);      // [q-local][d]
    for (int db = 0; db < 2; db++)
        for (int rq = 0; rq < 4; rq++) {
            u16x4 ov;
            for (int j = 0; j < 4; j++) ov[j] = f2b(o[db][rq * 4 + j]);
            *(u16x4*)&op[(w * 32 + l31) * 64 + db * 32 + rq * 8 + 4 * h] = ov;
        }
    if (h == 0)
        Plv[pid * 128 + w * 32 + l31] = oL[0];   // full k-sum for q (rows identical)
}

// ---------------- combine partials -> Z bf16 [4096][768] ----------------

__global__ __launch_bounds__(256) void combine(const u16* __restrict__ Po, const float* __restrict__ Plv,
                                               u16* __restrict__ Zb) {
    int qtile = blockIdx.x, bh = blockIdx.y;   // qtile in [0,16)
    int b = bh / NH, hH = bh % NH;
    int nc = qtile < 4 ? 1 : (qtile < 8 ? 2 : (qtile < 12 ? 3 : 4));
    int base = qtile < 4 ? qtile
             : (qtile < 8 ? 4 + (qtile - 4) * 2
             : (qtile < 12 ? 12 + (qtile - 8) * 3
                           : 24 + (qtile - 12) * 4));
    int t = threadIdx.x;
    int q = t >> 1, dseg = (t & 1) * 32;

    float acc[32] = {};
    float lsum = 0.f;
    for (int cc = 0; cc < nc; cc++) {
        size_t pid = (size_t)bh * NCHUNK + base + cc;
        lsum += Plv[pid * 128 + q];
        const u16* op = Po + pid * (128 * 64) + q * 64 + dseg;
        for (int jj = 0; jj < 4; jj++) {
            u16x8 v = *(const u16x8*)(op + jj * 8);
            for (int e = 0; e < 8; e++)
                acc[jj * 8 + e] += b2f(v[e]);
        }
    }
    float inv = 1.0f / lsum;
    u16* Zp = Zb + ((size_t)b * SLEN + qtile * 128 + q) * DM + hH * DH + dseg;
    for (int jj = 0; jj < 4; jj++) {
        u16x8 ov;
        for (int e = 0; e < 8; e++) ov[e] = f2b(acc[jj * 8 + e] * inv);
        *(u16x8*)(Zp + jj * 8) = ov;
    }
}

// ---------------- output projection (64x96 tile, global_load_lds staging) ----------------
// grid (8, 64) = 512 blocks = 2.0 blocks/CU exact.

__global__ __launch_bounds__(256) void gemm_proj(const u16* __restrict__ A, const u16* __restrict__ Bt,
                                                 const float* __restrict__ bO, float* __restrict__ out) {
    __shared__ u16 Al[64 * 64];
    __shared__ u16 Bl[96 * 64];
    int t = threadIdx.x;
    int n0 = blockIdx.x * 96, m0 = blockIdx.y * 64;
    int lane = t & 63, w = t >> 6;
    int ln = lane & 15, qd = lane >> 4;
    int wr = (w & 1) * 32, wc = (w >> 1) * 48;
    int srow = lane >> 3, slot = lane & 7;
    f32x4 acc[2][3] = {};

    for (int kt = 0; kt < DM / 64; kt++) {
        __syncthreads();
        for (int j = 0; j < 2; j++) {
            int r = w * 16 + j * 8 + srow;
            int gc = slot ^ (r & 7);
            gload16(A + (size_t)(m0 + r) * DM + kt * 64 + gc * 8, &Al[(w * 16 + j * 8) * 64]);
        }
        for (int j = 0; j < 3; j++) {
            int r = w * 24 + j * 8 + srow;
            int gc = slot ^ (r & 7);
            gload16(Bt + (size_t)(n0 + r) * DM + kt * 64 + gc * 8, &Bl[(w * 24 + j * 8) * 64]);
        }
        __syncthreads();
        for (int ks = 0; ks < 2; ks++) {
            int sl = ((ks * 4 + qd) ^ (ln & 7)) * 8;
            bf16x8 af[2], bfr[3];
            for (int rt = 0; rt < 2; rt++)
                af[rt] = *(const bf16x8*)&Al[(wr + rt * 16 + ln) * 64 + sl];
            for (int ct = 0; ct < 3; ct++)
                bfr[ct] = *(const bf16x8*)&Bl[(wc + ct * 16 + ln) * 64 + sl];
            for (int rt = 0; rt < 2; rt++)
                for (int ct = 0; ct < 3; ct++)
                    acc[rt][ct] = __builtin_amdgcn_mfma_f32_16x16x32_bf16(af[rt], bfr[ct], acc[rt][ct], 0, 0, 0);
        }
    }
    for (int ct = 0; ct < 3; ct++) {
        int col = n0 + wc + ct * 16 + ln;
        float bv = bO[col];
        for (int rt = 0; rt < 2; rt++) {
            int row = m0 + wr + rt * 16 + qd * 4;
            for (int r = 0; r < 4; r++)
                out[(size_t)(row + r) * DM + col] = acc[rt][ct][r] + bv;
        }
    }
}

// ---------------- launch ----------------

extern "C" void kernel_launch(void* const* d_in, const int* in_sizes, int n_in,
                              void* d_out, int out_size, void* d_ws, size_t ws_size,
                              hipStream_t stream) {
    const float* x  = (const float*)d_in[0];
    const float* WQ = (const float*)d_in[1];
    const float* bQ = (const float*)d_in[2];
    const float* WK = (const float*)d_in[3];
    const float* bK = (const float*)d_in[4];
    const float* WV = (const float*)d_in[5];
    const float* bV = (const float*)d_in[6];
    const float* WO = (const float*)d_in[7];
    const float* bO = (const float*)d_in[8];
    float* out = (float*)d_out;

    u16* xb   = (u16*)d_ws;                        // [4096][768]
    u16* wqkv = xb + (size_t)ROWS * DM;            // [2304][768]
    u16* wo   = wqkv + (size_t)NQKV * DM;          // [768][768]
    u16* Qb   = wo + (size_t)DM * DM;
    size_t hsz = (size_t)BATCH * NH * SLEN * DH;
    u16* Kb   = Qb + hsz;
    u16* Vb   = Kb + hsz;                          // V^T [b,h,d,s]
    u16* Zb   = Vb + hsz;                          // [4096][768]
    u16* Po   = Zb + (size_t)ROWS * DM;            // partials o: [24*40][128][64] bf16
    float* Pl = (float*)(Po + (size_t)BATCH * NH * NCHUNK * 128 * 64);

    pack_all<<<2112, 256, 0, stream>>>(x, WQ, WK, WV, WO, xb, wqkv, wo);
    gemm_qkv<<<dim3(NQKV / 96, ROWS / 128), 256, 0, stream>>>(xb, wqkv, bQ, bK, bV, Qb, Kb, Vb);
    attn<<<dim3(NCHUNK * 24), 256, 0, stream>>>(Qb, Kb, Vb, Po, Pl);
    combine<<<dim3(SLEN / 128, BATCH * NH), 256, 0, stream>>>(Po, Pl, Zb);
    gemm_proj<<<dim3(DM / 96, ROWS / 64), 256, 0, stream>>>(Zb, wo, bO, out);
}